// Round 1
// baseline (76.137 us; speedup 1.0000x reference)
//
#include <hip/hip_runtime.h>
#include <cstdint>
#include <cstddef>

#define B_ 4
#define N_ 16384
#define M_ 2048
#define C_ 64
#define S_ 32
#define J_ 67          // 3 + C
#define R2_ 0.04f
#define EPS_ 1e-5f

// ---------------------------------------------------------------------------
// K0: transpose features (B, C, N) -> featT (B, N, C) via LDS tile.
// Makes each sample's channel vector contiguous (256 B) for the gathers.
// ---------------------------------------------------------------------------
__global__ __launch_bounds__(256) void k_transpose(const float* __restrict__ feat,
                                                   float* __restrict__ featT) {
    __shared__ float tile[64][65];            // +1 pad: conflict-free transpose
    int b  = blockIdx.x >> 8;                 // N_/64 = 256 tiles per batch
    int n0 = (blockIdx.x & 255) << 6;
    int tid = threadIdx.x;
    int r = tid >> 6, i = tid & 63;
    const float* fb = feat + (size_t)b * C_ * N_;
    #pragma unroll
    for (int cc = r; cc < 64; cc += 4)
        tile[cc][i] = fb[(size_t)cc * N_ + n0 + i];     // coalesced read along n
    __syncthreads();
    float* ftb = featT + (size_t)b * N_ * C_;
    #pragma unroll
    for (int nn = r; nn < 64; nn += 4)
        ftb[(size_t)(n0 + nn) * C_ + i] = tile[i][nn];  // coalesced write along c
}

// ---------------------------------------------------------------------------
// K1: ball query (one wave per center) + per-center partial sums of the
// centered values (for the per-batch std). Deterministic: no atomics.
// ---------------------------------------------------------------------------
__global__ __launch_bounds__(64) void k_ballquery(
        const float* __restrict__ pts, const float* __restrict__ ctr,
        const float* __restrict__ featT, const float* __restrict__ cfeat,
        int* __restrict__ idx_ws, float* __restrict__ partials) {
    int bm = blockIdx.x;
    int b  = bm >> 11;                        // M_ = 2048
    int lane = threadIdx.x;                   // 0..63
    const float* pb = pts + (size_t)b * N_ * 3;
    float cx = ctr[(size_t)bm * 3 + 0];
    float cy = ctr[(size_t)bm * 3 + 1];
    float cz = ctr[(size_t)bm * 3 + 2];

    __shared__ int sidx[S_];
    int cnt = 0;
    for (int base = 0; base < N_; base += 64) {
        int i = base + lane;
        // bit-exact vs numpy: no FMA contraction, (x^2 + y^2) + z^2 order
        float dx = __fsub_rn(cx, pb[i * 3 + 0]);
        float dy = __fsub_rn(cy, pb[i * 3 + 1]);
        float dz = __fsub_rn(cz, pb[i * 3 + 2]);
        float d2 = __fadd_rn(__fadd_rn(__fmul_rn(dx, dx), __fmul_rn(dy, dy)),
                             __fmul_rn(dz, dz));
        bool in = d2 < R2_;                   // MIN_RADIUS=0: lower bound always true
        unsigned long long mk = __ballot(in);
        int rank = __popcll(mk & ((1ull << lane) - 1ull));
        int pos = cnt + rank;
        if (in && pos < S_) sidx[pos] = i;    // ascending index order == top_k result
        cnt += __popcll(mk);
        if (cnt >= S_) break;                 // wave-uniform early exit
    }
    __syncthreads();
    int cfound = cnt < S_ ? cnt : S_;
    if (lane < S_) {
        int first = (cfound > 0) ? sidx[0] : 0;   // empty ball -> all zeros (ref semantics)
        int v = (lane < cfound) ? sidx[lane] : first;
        sidx[lane] = v;
        idx_ws[(size_t)bm * S_ + lane] = v;
    }
    __syncthreads();

    // --- partial sums of centered values (features: lane = channel, coalesced rows)
    const float* ftb = featT + (size_t)b * N_ * C_;
    float cf = cfeat[(size_t)bm * C_ + lane];
    float s1 = 0.f, s2 = 0.f;
    #pragma unroll 4
    for (int s = 0; s < S_; s++) {
        int p = sidx[s];
        float v = ftb[(size_t)p * C_ + lane] - cf;
        s1 += v; s2 += v * v;
    }
    if (lane < 3) {                           // xyz part
        float cc = ctr[(size_t)bm * 3 + lane];
        for (int s = 0; s < S_; s++) {
            int p = sidx[s];
            float v = pb[p * 3 + lane] - cc;
            s1 += v; s2 += v * v;
        }
    }
    #pragma unroll
    for (int off = 32; off > 0; off >>= 1) {
        s1 += __shfl_down(s1, off);
        s2 += __shfl_down(s2, off);
    }
    if (lane == 0) {
        partials[(size_t)bm * 2 + 0] = s1;
        partials[(size_t)bm * 2 + 1] = s2;
    }
}

// ---------------------------------------------------------------------------
// K2: per-batch reduce of partials -> inv = 1/(std+eps)  (deterministic tree)
// ---------------------------------------------------------------------------
__global__ __launch_bounds__(256) void k_reduce(const float* __restrict__ partials,
                                                float* __restrict__ accum) {
    int b = blockIdx.x, tid = threadIdx.x;
    float s1 = 0.f, s2 = 0.f;
    for (int i = tid; i < M_; i += 256) {
        s1 += partials[((size_t)b * M_ + i) * 2 + 0];
        s2 += partials[((size_t)b * M_ + i) * 2 + 1];
    }
    __shared__ float l1[256], l2[256];
    l1[tid] = s1; l2[tid] = s2;
    __syncthreads();
    for (int off = 128; off > 0; off >>= 1) {
        if (tid < off) { l1[tid] += l1[tid + off]; l2[tid] += l2[tid + off]; }
        __syncthreads();
    }
    if (tid == 0) {
        float sum = l1[0], sumsq = l2[0];
        const float n = (float)(M_ * S_ * J_);          // 4390912 < 2^24, exact
        float mean = sum / n;
        float var  = (sumsq - sum * mean) / (n - 1.f);  // ddof = 1
        accum[b] = 1.f / (sqrtf(var) + EPS_);
    }
}

// ---------------------------------------------------------------------------
// K3: write output (B, 67, M, S). Thread = (m-in-tile, s); loops channels.
// Gather reads are 256 B contiguous per thread (featT); writes coalesced.
// ---------------------------------------------------------------------------
__global__ __launch_bounds__(256) void k_output(
        const float* __restrict__ pts, const float* __restrict__ ctr,
        const float* __restrict__ featT, const float* __restrict__ cfeat,
        const float* __restrict__ alpha, const float* __restrict__ beta,
        const int* __restrict__ idx_ws, const float* __restrict__ accum,
        float* __restrict__ out) {
    int blk = blockIdx.x;
    int b  = blk >> 8;                         // M_/8 = 256 tiles per batch
    int mt = blk & 255;
    int tid = threadIdx.x;
    int mi = tid >> 5;                         // 0..7
    int s  = tid & 31;
    int m  = mt * 8 + mi;
    size_t bm = (size_t)b * M_ + m;
    int p = idx_ws[bm * S_ + s];
    float inv = accum[b];

    const float* pb = pts + (size_t)b * N_ * 3;
    size_t obase = ((size_t)b * J_ * M_ + m) * S_ + s;
    #pragma unroll
    for (int j = 0; j < 3; j++) {
        float v = pb[p * 3 + j] - ctr[bm * 3 + j];
        out[obase + (size_t)j * M_ * S_] = alpha[j] * inv * v + beta[j];
    }
    const float4* fr4 = (const float4*)(featT + ((size_t)b * N_ + p) * C_);
    const float4* cf4 = (const float4*)(cfeat + bm * C_);
    #pragma unroll
    for (int cq = 0; cq < 16; cq++) {
        float4 fv = fr4[cq];
        float4 cv = cf4[cq];
        int j = 3 + cq * 4;
        out[obase + (size_t)(j + 0) * M_ * S_] = alpha[j + 0] * inv * (fv.x - cv.x) + beta[j + 0];
        out[obase + (size_t)(j + 1) * M_ * S_] = alpha[j + 1] * inv * (fv.y - cv.y) + beta[j + 1];
        out[obase + (size_t)(j + 2) * M_ * S_] = alpha[j + 2] * inv * (fv.z - cv.z) + beta[j + 2];
        out[obase + (size_t)(j + 3) * M_ * S_] = alpha[j + 3] * inv * (fv.w - cv.w) + beta[j + 3];
    }
}

// ---------------------------------------------------------------------------
extern "C" void kernel_launch(void* const* d_in, const int* in_sizes, int n_in,
                              void* d_out, int out_size, void* d_ws, size_t ws_size,
                              hipStream_t stream) {
    const float* pts   = (const float*)d_in[0];   // (B,N,3)
    const float* ctr   = (const float*)d_in[1];   // (B,M,3)
    const float* cfeat = (const float*)d_in[2];   // (B,M,C)
    const float* feat  = (const float*)d_in[3];   // (B,C,N)
    const float* alpha = (const float*)d_in[4];   // (67)
    const float* beta  = (const float*)d_in[5];   // (67)
    float* out = (float*)d_out;

    // workspace layout (all 16B-aligned):
    //   featT    : B*N*C floats   = 16 MB
    //   idx_ws   : B*M*S int32    =  1 MB
    //   partials : B*M*2 floats   = 64 KB
    //   accum    : B floats
    char* ws = (char*)d_ws;
    float* featT    = (float*)ws;
    int*   idx_ws   = (int*)(ws + (size_t)B_ * N_ * C_ * 4);
    float* partials = (float*)(ws + (size_t)B_ * N_ * C_ * 4 + (size_t)B_ * M_ * S_ * 4);
    float* accum    = partials + (size_t)B_ * M_ * 2;

    k_transpose<<<B_ * (N_ / 64), 256, 0, stream>>>(feat, featT);
    k_ballquery<<<B_ * M_, 64, 0, stream>>>(pts, ctr, featT, cfeat, idx_ws, partials);
    k_reduce<<<B_, 256, 0, stream>>>(partials, accum);
    k_output<<<B_ * (M_ / 8), 256, 0, stream>>>(pts, ctr, featT, cfeat, alpha, beta,
                                                idx_ws, accum, out);
}

// Round 2
// 57.207 us; speedup vs baseline: 1.3309x; 1.3309x over previous
//
#include <hip/hip_runtime.h>
#include <cstdint>
#include <cstddef>

#define B_ 4
#define N_ 16384
#define M_ 2048
#define C_ 64
#define S_ 32
#define J_ 67          // 3 + C
#define R2_ 0.04f
#define EPS_ 1e-5f
#define WPB_ 4         // waves (centers) per block in k_ballquery

// ---------------------------------------------------------------------------
// K0: transpose features (B, C, N) -> featT (B, N, C) via LDS tile.
// Makes each sample's channel vector contiguous (256 B) for the gathers.
// ---------------------------------------------------------------------------
__global__ __launch_bounds__(256) void k_transpose(const float* __restrict__ feat,
                                                   float* __restrict__ featT) {
    __shared__ float tile[64][65];            // +1 pad: conflict-free transpose
    int b  = blockIdx.x >> 8;                 // N_/64 = 256 tiles per batch
    int n0 = (blockIdx.x & 255) << 6;
    int tid = threadIdx.x;
    int r = tid >> 6, i = tid & 63;
    const float* fb = feat + (size_t)b * C_ * N_;
    #pragma unroll
    for (int cc = r; cc < 64; cc += 4)
        tile[cc][i] = fb[(size_t)cc * N_ + n0 + i];     // coalesced read along n
    __syncthreads();
    float* ftb = featT + (size_t)b * N_ * C_;
    #pragma unroll
    for (int nn = r; nn < 64; nn += 4)
        ftb[(size_t)(n0 + nn) * C_ + i] = tile[i][nn];  // coalesced write along c
}

// ---------------------------------------------------------------------------
// K1: ball query (one wave per center, 4 waves per block) + per-center
// partial sums of the centered values. Deterministic: no atomics.
// Scan is batched 256 points/trip: 12 independent loads issued up front,
// then 4 in-order ballot rounds -> dependent-latency chain cut ~4x.
// ---------------------------------------------------------------------------
__global__ __launch_bounds__(256) void k_ballquery(
        const float* __restrict__ pts, const float* __restrict__ ctr,
        const float* __restrict__ featT, const float* __restrict__ cfeat,
        int* __restrict__ idx_ws, float* __restrict__ partials) {
    int w    = threadIdx.x >> 6;              // wave id in block
    int lane = threadIdx.x & 63;
    int bm   = blockIdx.x * WPB_ + w;
    int b    = bm >> 11;                      // M_ = 2048
    const float* pb = pts + (size_t)b * N_ * 3;
    float cx = ctr[(size_t)bm * 3 + 0];
    float cy = ctr[(size_t)bm * 3 + 1];
    float cz = ctr[(size_t)bm * 3 + 2];

    __shared__ int sidx[WPB_][S_];
    int cnt = 0;
    for (int base = 0; base < N_; base += 256) {
        float xs[4], ys[4], zs[4];
        #pragma unroll
        for (int r = 0; r < 4; r++) {         // 12 independent loads in flight
            int i = base + r * 64 + lane;
            xs[r] = pb[i * 3 + 0];
            ys[r] = pb[i * 3 + 1];
            zs[r] = pb[i * 3 + 2];
        }
        #pragma unroll
        for (int r = 0; r < 4; r++) {
            // bit-exact vs numpy: no FMA contraction, (x^2 + y^2) + z^2 order
            float dx = __fsub_rn(cx, xs[r]);
            float dy = __fsub_rn(cy, ys[r]);
            float dz = __fsub_rn(cz, zs[r]);
            float d2 = __fadd_rn(__fadd_rn(__fmul_rn(dx, dx), __fmul_rn(dy, dy)),
                                 __fmul_rn(dz, dz));
            bool in = d2 < R2_;               // MIN_RADIUS=0: lower bound always true
            unsigned long long mk = __ballot(in);
            int rank = __popcll(mk & ((1ull << lane) - 1ull));
            int pos = cnt + rank;
            if (in && pos < S_) sidx[w][pos] = base + r * 64 + lane;
            cnt += __popcll(mk);
            if (cnt >= S_) break;             // wave-uniform
        }
        if (cnt >= S_) break;                 // wave-uniform early exit
    }
    __syncthreads();                          // all 4 waves converged here
    int cfound = cnt < S_ ? cnt : S_;
    if (lane < S_) {
        int first = (cfound > 0) ? sidx[w][0] : 0;  // empty ball -> zeros (ref semantics)
        int v = (lane < cfound) ? sidx[w][lane] : first;
        sidx[w][lane] = v;
        idx_ws[(size_t)bm * S_ + lane] = v;
    }
    __syncthreads();

    // --- partial sums of centered values (features: lane = channel, coalesced rows)
    // NOTE: summation order identical to round-1 kernel -> bitwise-stable std.
    const float* ftb = featT + (size_t)b * N_ * C_;
    float cf = cfeat[(size_t)bm * C_ + lane];
    float s1 = 0.f, s2 = 0.f;
    #pragma unroll 4
    for (int s = 0; s < S_; s++) {
        int p = sidx[w][s];
        float v = ftb[(size_t)p * C_ + lane] - cf;
        s1 += v; s2 += v * v;
    }
    if (lane < 3) {                           // xyz part
        float cc = ctr[(size_t)bm * 3 + lane];
        for (int s = 0; s < S_; s++) {
            int p = sidx[w][s];
            float v = pb[p * 3 + lane] - cc;
            s1 += v; s2 += v * v;
        }
    }
    #pragma unroll
    for (int off = 32; off > 0; off >>= 1) {
        s1 += __shfl_down(s1, off);
        s2 += __shfl_down(s2, off);
    }
    if (lane == 0) {
        partials[(size_t)bm * 2 + 0] = s1;
        partials[(size_t)bm * 2 + 1] = s2;
    }
}

// ---------------------------------------------------------------------------
// K2: per-batch reduce of partials -> inv = 1/(std+eps)  (deterministic tree)
// ---------------------------------------------------------------------------
__global__ __launch_bounds__(256) void k_reduce(const float* __restrict__ partials,
                                                float* __restrict__ accum) {
    int b = blockIdx.x, tid = threadIdx.x;
    float s1 = 0.f, s2 = 0.f;
    for (int i = tid; i < M_; i += 256) {
        s1 += partials[((size_t)b * M_ + i) * 2 + 0];
        s2 += partials[((size_t)b * M_ + i) * 2 + 1];
    }
    __shared__ float l1[256], l2[256];
    l1[tid] = s1; l2[tid] = s2;
    __syncthreads();
    for (int off = 128; off > 0; off >>= 1) {
        if (tid < off) { l1[tid] += l1[tid + off]; l2[tid] += l2[tid + off]; }
        __syncthreads();
    }
    if (tid == 0) {
        float sum = l1[0], sumsq = l2[0];
        const float n = (float)(M_ * S_ * J_);          // 4390912 < 2^24, exact
        float mean = sum / n;
        float var  = (sumsq - sum * mean) / (n - 1.f);  // ddof = 1
        accum[b] = 1.f / (sqrtf(var) + EPS_);
    }
}

// ---------------------------------------------------------------------------
// K3: write output (B, 67, M, S). Thread = (m-in-tile, s); loops channels.
// Gather reads are 256 B contiguous per thread (featT); writes coalesced.
// ---------------------------------------------------------------------------
__global__ __launch_bounds__(256) void k_output(
        const float* __restrict__ pts, const float* __restrict__ ctr,
        const float* __restrict__ featT, const float* __restrict__ cfeat,
        const float* __restrict__ alpha, const float* __restrict__ beta,
        const int* __restrict__ idx_ws, const float* __restrict__ accum,
        float* __restrict__ out) {
    int blk = blockIdx.x;
    int b  = blk >> 8;                         // M_/8 = 256 tiles per batch
    int mt = blk & 255;
    int tid = threadIdx.x;
    int mi = tid >> 5;                         // 0..7
    int s  = tid & 31;
    int m  = mt * 8 + mi;
    size_t bm = (size_t)b * M_ + m;
    int p = idx_ws[bm * S_ + s];
    float inv = accum[b];

    const float* pb = pts + (size_t)b * N_ * 3;
    size_t obase = ((size_t)b * J_ * M_ + m) * S_ + s;
    #pragma unroll
    for (int j = 0; j < 3; j++) {
        float v = pb[p * 3 + j] - ctr[bm * 3 + j];
        out[obase + (size_t)j * M_ * S_] = alpha[j] * inv * v + beta[j];
    }
    const float4* fr4 = (const float4*)(featT + ((size_t)b * N_ + p) * C_);
    const float4* cf4 = (const float4*)(cfeat + bm * C_);
    #pragma unroll
    for (int cq = 0; cq < 16; cq++) {
        float4 fv = fr4[cq];
        float4 cv = cf4[cq];
        int j = 3 + cq * 4;
        out[obase + (size_t)(j + 0) * M_ * S_] = alpha[j + 0] * inv * (fv.x - cv.x) + beta[j + 0];
        out[obase + (size_t)(j + 1) * M_ * S_] = alpha[j + 1] * inv * (fv.y - cv.y) + beta[j + 1];
        out[obase + (size_t)(j + 2) * M_ * S_] = alpha[j + 2] * inv * (fv.z - cv.z) + beta[j + 2];
        out[obase + (size_t)(j + 3) * M_ * S_] = alpha[j + 3] * inv * (fv.w - cv.w) + beta[j + 3];
    }
}

// ---------------------------------------------------------------------------
extern "C" void kernel_launch(void* const* d_in, const int* in_sizes, int n_in,
                              void* d_out, int out_size, void* d_ws, size_t ws_size,
                              hipStream_t stream) {
    const float* pts   = (const float*)d_in[0];   // (B,N,3)
    const float* ctr   = (const float*)d_in[1];   // (B,M,3)
    const float* cfeat = (const float*)d_in[2];   // (B,M,C)
    const float* feat  = (const float*)d_in[3];   // (B,C,N)
    const float* alpha = (const float*)d_in[4];   // (67)
    const float* beta  = (const float*)d_in[5];   // (67)
    float* out = (float*)d_out;

    char* ws = (char*)d_ws;
    float* featT    = (float*)ws;                                   // 16 MB
    int*   idx_ws   = (int*)(ws + (size_t)B_ * N_ * C_ * 4);        //  1 MB
    float* partials = (float*)(ws + (size_t)B_ * N_ * C_ * 4 + (size_t)B_ * M_ * S_ * 4);
    float* accum    = partials + (size_t)B_ * M_ * 2;

    k_transpose<<<B_ * (N_ / 64), 256, 0, stream>>>(feat, featT);
    k_ballquery<<<B_ * M_ / WPB_, 256, 0, stream>>>(pts, ctr, featT, cfeat, idx_ws, partials);
    k_reduce<<<B_, 256, 0, stream>>>(partials, accum);
    k_output<<<B_ * (M_ / 8), 256, 0, stream>>>(pts, ctr, featT, cfeat, alpha, beta,
                                                idx_ws, accum, out);
}

// Round 3
// 51.567 us; speedup vs baseline: 1.4765x; 1.1094x over previous
//
#include <hip/hip_runtime.h>
#include <cstdint>
#include <cstddef>

#define B_ 4
#define N_ 16384
#define M_ 2048
#define C_ 64
#define S_ 32
#define J_ 67          // 3 + C
#define R2_ 0.04f
#define EPS_ 1e-5f

// ---------------------------------------------------------------------------
// KA: fused independent phases.
//   blocks [0, 1024):    transpose features (B,C,N) -> featT (B,N,C)
//   blocks [1024, 3072): ball-query scan (idx only), 4 centers/block (1/wave)
// The scan does NOT touch featT, so both roles run concurrently.
// ---------------------------------------------------------------------------
__global__ __launch_bounds__(256) void k_phase1(
        const float* __restrict__ feat, float* __restrict__ featT,
        const float* __restrict__ pts, const float* __restrict__ ctr,
        int* __restrict__ idx_ws) {
    __shared__ float tile[64][65];            // transpose tile; scan aliases sidx
    int blk = blockIdx.x;
    int tid = threadIdx.x;

    if (blk < 1024) {
        // ---- transpose role ----
        int b  = blk >> 8;                    // N_/64 = 256 tiles per batch
        int n0 = (blk & 255) << 6;
        int r = tid >> 6, i = tid & 63;
        const float* fb = feat + (size_t)b * C_ * N_;
        #pragma unroll
        for (int cc = r; cc < 64; cc += 4)
            tile[cc][i] = fb[(size_t)cc * N_ + n0 + i];     // coalesced read
        __syncthreads();
        float* ftb = featT + (size_t)b * N_ * C_;
        #pragma unroll
        for (int nn = r; nn < 64; nn += 4)
            ftb[(size_t)(n0 + nn) * C_ + i] = tile[i][nn];  // coalesced write
        return;
    }

    // ---- ball-query scan role (idx only) ----
    int* sidx = (int*)&tile[0][0];            // [4][S_] per-wave slots
    int w    = tid >> 6;
    int lane = tid & 63;
    int bm   = (blk - 1024) * 4 + w;
    int b    = bm >> 11;                      // M_ = 2048
    const float* pb = pts + (size_t)b * N_ * 3;
    float cx = ctr[(size_t)bm * 3 + 0];
    float cy = ctr[(size_t)bm * 3 + 1];
    float cz = ctr[(size_t)bm * 3 + 2];

    // software-pipelined scan: issue trip t+1 loads before processing trip t
    float xs[4], ys[4], zs[4], xn[4], yn[4], zn[4];
    #pragma unroll
    for (int r = 0; r < 4; r++) {
        int i = r * 64 + lane;
        xs[r] = pb[i * 3 + 0]; ys[r] = pb[i * 3 + 1]; zs[r] = pb[i * 3 + 2];
    }
    int cnt = 0;
    for (int base = 0; base < N_; base += 256) {
        int nxt = base + 256;
        if (nxt < N_) {
            #pragma unroll
            for (int r = 0; r < 4; r++) {     // prefetch next trip (independent)
                int i = nxt + r * 64 + lane;
                xn[r] = pb[i * 3 + 0]; yn[r] = pb[i * 3 + 1]; zn[r] = pb[i * 3 + 2];
            }
        }
        #pragma unroll
        for (int r = 0; r < 4; r++) {
            // bit-exact vs numpy: no FMA contraction, (x^2 + y^2) + z^2 order
            float dx = __fsub_rn(cx, xs[r]);
            float dy = __fsub_rn(cy, ys[r]);
            float dz = __fsub_rn(cz, zs[r]);
            float d2 = __fadd_rn(__fadd_rn(__fmul_rn(dx, dx), __fmul_rn(dy, dy)),
                                 __fmul_rn(dz, dz));
            bool in = d2 < R2_;               // MIN_RADIUS=0: lower bound always true
            unsigned long long mk = __ballot(in);
            int rank = __popcll(mk & ((1ull << lane) - 1ull));
            int pos = cnt + rank;
            if (in && pos < S_) sidx[w * S_ + pos] = base + r * 64 + lane;
            cnt += __popcll(mk);
            if (cnt >= S_) break;             // wave-uniform
        }
        if (cnt >= S_ || nxt >= N_) break;
        #pragma unroll
        for (int r = 0; r < 4; r++) { xs[r] = xn[r]; ys[r] = yn[r]; zs[r] = zn[r]; }
    }
    __syncthreads();                          // order LDS scatter vs cross-lane read
    int cfound = cnt < S_ ? cnt : S_;
    if (lane < S_) {
        int first = (cfound > 0) ? sidx[w * S_] : 0;    // empty ball -> zeros
        int v = (lane < cfound) ? sidx[w * S_ + lane] : first;
        idx_ws[(size_t)bm * S_ + lane] = v;             // padded idx (ref semantics)
    }
}

// ---------------------------------------------------------------------------
// KB: per-center partial sums of centered values (std numerator terms).
// 2 centers per wave; featT rows gathered 256 B coalesced, 32 loads in flight.
// Sum order is reassociated vs reference — only feeds the scalar std (loose tol).
// ---------------------------------------------------------------------------
__global__ __launch_bounds__(256) void k_sums(
        const float* __restrict__ pts, const float* __restrict__ ctr,
        const float* __restrict__ featT, const float* __restrict__ cfeat,
        const int* __restrict__ idx_ws, float* __restrict__ partials) {
    int w    = threadIdx.x >> 6;
    int lane = threadIdx.x & 63;
    #pragma unroll
    for (int cc = 0; cc < 2; cc++) {
        int bm = blockIdx.x * 8 + w * 2 + cc;
        int b  = bm >> 11;
        const float* pb  = pts + (size_t)b * N_ * 3;
        const float* ftb = featT + (size_t)b * N_ * C_;
        int id = idx_ws[(size_t)bm * S_ + (lane & 31)];  // lane's sample idx
        float cf = cfeat[(size_t)bm * C_ + lane];
        float cx = ctr[(size_t)bm * 3 + 0];
        float cy = ctr[(size_t)bm * 3 + 1];
        float cz = ctr[(size_t)bm * 3 + 2];

        float s1 = 0.f, s2 = 0.f;
        float v[S_];
        #pragma unroll
        for (int s = 0; s < S_; s++) {        // 32 independent coalesced loads
            int p = __shfl(id, s);            // broadcast sample s's point idx
            v[s] = ftb[(size_t)p * C_ + lane];
        }
        #pragma unroll
        for (int s = 0; s < S_; s++) {
            float d = v[s] - cf;
            s1 += d; s2 += d * d;
        }
        // xyz part spread across lanes: half 0 -> x (+z), half 1 -> y
        float cj = (lane < 32) ? cx : cy;
        float pv = pb[id * 3 + (lane >> 5)];
        float d = pv - cj; s1 += d; s2 += d * d;
        if (lane < 32) {
            float dz = pb[id * 3 + 2] - cz;
            s1 += dz; s2 += dz * dz;
        }
        #pragma unroll
        for (int off = 32; off > 0; off >>= 1) {
            s1 += __shfl_down(s1, off);
            s2 += __shfl_down(s2, off);
        }
        if (lane == 0) {
            partials[(size_t)bm * 2 + 0] = s1;
            partials[(size_t)bm * 2 + 1] = s2;
        }
    }
}

// ---------------------------------------------------------------------------
// K2: per-batch reduce of partials -> inv = 1/(std+eps)  (deterministic tree)
// ---------------------------------------------------------------------------
__global__ __launch_bounds__(256) void k_reduce(const float* __restrict__ partials,
                                                float* __restrict__ accum) {
    int b = blockIdx.x, tid = threadIdx.x;
    float s1 = 0.f, s2 = 0.f;
    for (int i = tid; i < M_; i += 256) {
        s1 += partials[((size_t)b * M_ + i) * 2 + 0];
        s2 += partials[((size_t)b * M_ + i) * 2 + 1];
    }
    __shared__ float l1[256], l2[256];
    l1[tid] = s1; l2[tid] = s2;
    __syncthreads();
    for (int off = 128; off > 0; off >>= 1) {
        if (tid < off) { l1[tid] += l1[tid + off]; l2[tid] += l2[tid + off]; }
        __syncthreads();
    }
    if (tid == 0) {
        float sum = l1[0], sumsq = l2[0];
        const float n = (float)(M_ * S_ * J_);          // 4390912 < 2^24, exact
        float mean = sum / n;
        float var  = (sumsq - sum * mean) / (n - 1.f);  // ddof = 1
        accum[b] = 1.f / (sqrtf(var) + EPS_);
    }
}

// ---------------------------------------------------------------------------
// K3: write output (B, 67, M, S). Thread = (m-in-tile, s); loops channels.
// Gather reads are 256 B contiguous per thread (featT); writes coalesced.
// ---------------------------------------------------------------------------
__global__ __launch_bounds__(256) void k_output(
        const float* __restrict__ pts, const float* __restrict__ ctr,
        const float* __restrict__ featT, const float* __restrict__ cfeat,
        const float* __restrict__ alpha, const float* __restrict__ beta,
        const int* __restrict__ idx_ws, const float* __restrict__ accum,
        float* __restrict__ out) {
    int blk = blockIdx.x;
    int b  = blk >> 8;                         // M_/8 = 256 tiles per batch
    int mt = blk & 255;
    int tid = threadIdx.x;
    int mi = tid >> 5;                         // 0..7
    int s  = tid & 31;
    int m  = mt * 8 + mi;
    size_t bm = (size_t)b * M_ + m;
    int p = idx_ws[bm * S_ + s];
    float inv = accum[b];

    const float* pb = pts + (size_t)b * N_ * 3;
    size_t obase = ((size_t)b * J_ * M_ + m) * S_ + s;
    #pragma unroll
    for (int j = 0; j < 3; j++) {
        float v = pb[p * 3 + j] - ctr[bm * 3 + j];
        out[obase + (size_t)j * M_ * S_] = alpha[j] * inv * v + beta[j];
    }
    const float4* fr4 = (const float4*)(featT + ((size_t)b * N_ + p) * C_);
    const float4* cf4 = (const float4*)(cfeat + bm * C_);
    #pragma unroll
    for (int cq = 0; cq < 16; cq++) {
        float4 fv = fr4[cq];
        float4 cv = cf4[cq];
        int j = 3 + cq * 4;
        out[obase + (size_t)(j + 0) * M_ * S_] = alpha[j + 0] * inv * (fv.x - cv.x) + beta[j + 0];
        out[obase + (size_t)(j + 1) * M_ * S_] = alpha[j + 1] * inv * (fv.y - cv.y) + beta[j + 1];
        out[obase + (size_t)(j + 2) * M_ * S_] = alpha[j + 2] * inv * (fv.z - cv.z) + beta[j + 2];
        out[obase + (size_t)(j + 3) * M_ * S_] = alpha[j + 3] * inv * (fv.w - cv.w) + beta[j + 3];
    }
}

// ---------------------------------------------------------------------------
extern "C" void kernel_launch(void* const* d_in, const int* in_sizes, int n_in,
                              void* d_out, int out_size, void* d_ws, size_t ws_size,
                              hipStream_t stream) {
    const float* pts   = (const float*)d_in[0];   // (B,N,3)
    const float* ctr   = (const float*)d_in[1];   // (B,M,3)
    const float* cfeat = (const float*)d_in[2];   // (B,M,C)
    const float* feat  = (const float*)d_in[3];   // (B,C,N)
    const float* alpha = (const float*)d_in[4];   // (67)
    const float* beta  = (const float*)d_in[5];   // (67)
    float* out = (float*)d_out;

    char* ws = (char*)d_ws;
    float* featT    = (float*)ws;                                   // 16 MB
    int*   idx_ws   = (int*)(ws + (size_t)B_ * N_ * C_ * 4);        //  1 MB
    float* partials = (float*)(ws + (size_t)B_ * N_ * C_ * 4 + (size_t)B_ * M_ * S_ * 4);
    float* accum    = partials + (size_t)B_ * M_ * 2;

    k_phase1<<<3072, 256, 0, stream>>>(feat, featT, pts, ctr, idx_ws);
    k_sums<<<B_ * M_ / 8, 256, 0, stream>>>(pts, ctr, featT, cfeat, idx_ws, partials);
    k_reduce<<<B_, 256, 0, stream>>>(partials, accum);
    k_output<<<B_ * (M_ / 8), 256, 0, stream>>>(pts, ctr, featT, cfeat, alpha, beta,
                                                idx_ws, accum, out);
}